// Round 3
// baseline (50.957 us; speedup 1.0000x reference)
//
#include <hip/hip_runtime.h>

// out[n, d] = x[n, d] * weight[d] + bias[d]
// x: (8192, 4096) fp32, weight/bias: (4096,) fp32, out: (8192, 4096) fp32.
// Memory-bound: 128 MiB read + 128 MiB write -> roofline ~42.6 us @ 6.3 TB/s.
// R1: 45.95 us (93% of achievable). R2: nontemporal x-load / out-store via
// native ext_vector type (HIP_vector_type rejected by the builtin).

typedef float f32x4 __attribute__((ext_vector_type(4)));

constexpr int kD = 4096;
constexpr int kTokens = 8192;
constexpr long long kN = (long long)kTokens * kD;      // 33554432 elements
constexpr int kNVec = (int)(kN / 4);                   // 8388608 float4s
constexpr int kDVec = kD / 4;                          // 1024 float4s per row

__global__ __launch_bounds__(256) void DiagonalLinear_kernel(
    const float* __restrict__ x,
    const float* __restrict__ w,
    const float* __restrict__ b,
    float* __restrict__ out) {
    const f32x4* __restrict__ x4 = reinterpret_cast<const f32x4*>(x);
    const f32x4* __restrict__ w4 = reinterpret_cast<const f32x4*>(w);
    const f32x4* __restrict__ b4 = reinterpret_cast<const f32x4*>(b);
    f32x4* __restrict__ o4 = reinterpret_cast<f32x4*>(out);

    const int start = blockIdx.x * blockDim.x + threadIdx.x;
    const int stride = gridDim.x * blockDim.x;  // 524288 = multiple of kDVec

    // stride % kDVec == 0 -> column index is invariant across the loop.
    const int c = start & (kDVec - 1);
    const f32x4 wv = w4[c];   // cached (16 KiB, L1/L2-resident)
    const f32x4 bv = b4[c];

    for (int i = start; i < kNVec; i += stride) {
        f32x4 xv = __builtin_nontemporal_load(&x4[i]);   // streamed once
        f32x4 ov;
        ov.x = fmaf(xv.x, wv.x, bv.x);
        ov.y = fmaf(xv.y, wv.y, bv.y);
        ov.z = fmaf(xv.z, wv.z, bv.z);
        ov.w = fmaf(xv.w, wv.w, bv.w);
        __builtin_nontemporal_store(ov, &o4[i]);         // streamed once
    }
}

extern "C" void kernel_launch(void* const* d_in, const int* in_sizes, int n_in,
                              void* d_out, int out_size, void* d_ws, size_t ws_size,
                              hipStream_t stream) {
    const float* x = (const float*)d_in[0];
    const float* w = (const float*)d_in[1];
    const float* b = (const float*)d_in[2];
    float* out = (float*)d_out;

    const int block = 256;
    const int grid = 2048;  // 8 blocks/CU x 4 waves = 32 waves/CU (max occupancy)
    DiagonalLinear_kernel<<<grid, block, 0, stream>>>(x, w, b, out);
}

// Round 4
// 46.958 us; speedup vs baseline: 1.0851x; 1.0851x over previous
//
#include <hip/hip_runtime.h>

// out[n, d] = x[n, d] * weight[d] + bias[d]
// x: (8192, 4096) fp32, weight/bias: (4096,) fp32, out: (8192, 4096) fp32.
// Memory-bound: 128 MiB read + 128 MiB write -> roofline ~42.6 us @ 6.3 TB/s
// (float4-copy ceiling; write-only fill reaches 7.2 TB/s but r+w mix pays
// bus turnaround).
// R1: 45.95 us cached path (93%). R2/R3: nontemporal ld/st -> 50.96 us
// (REGRESSED ~10%: nt bypasses L2 write-combining; reverted).
// R4: cached path + compile-time 16-trip loop, unroll 4 for VMEM ILP.

typedef float f32x4 __attribute__((ext_vector_type(4)));

constexpr int kD = 4096;
constexpr int kTokens = 8192;
constexpr long long kN = (long long)kTokens * kD;      // 33554432 elements
constexpr int kNVec = (int)(kN / 4);                   // 8388608 float4s
constexpr int kDVec = kD / 4;                          // 1024 float4s per row
constexpr int kGrid = 2048;
constexpr int kBlock = 256;
constexpr int kStride = kGrid * kBlock;                // 524288, multiple of kDVec
constexpr int kIters = kNVec / kStride;                // exactly 16

static_assert(kNVec % kStride == 0, "exact tiling");
static_assert(kStride % kDVec == 0, "column invariant across iterations");

__global__ __launch_bounds__(kBlock) void DiagonalLinear_kernel(
    const float* __restrict__ x,
    const float* __restrict__ w,
    const float* __restrict__ b,
    float* __restrict__ out) {
    const f32x4* __restrict__ x4 = reinterpret_cast<const f32x4*>(x);
    const f32x4* __restrict__ w4 = reinterpret_cast<const f32x4*>(w);
    const f32x4* __restrict__ b4 = reinterpret_cast<const f32x4*>(b);
    f32x4* __restrict__ o4 = reinterpret_cast<f32x4*>(out);

    const int start = blockIdx.x * blockDim.x + threadIdx.x;

    // stride % kDVec == 0 -> column index is invariant across the loop.
    const int c = start & (kDVec - 1);
    const f32x4 wv = w4[c];   // cached (16 KiB, L1/L2-resident)
    const f32x4 bv = b4[c];

#pragma unroll 4
    for (int k = 0; k < kIters; ++k) {
        const int i = start + k * kStride;
        f32x4 xv = x4[i];
        f32x4 ov;
        ov.x = fmaf(xv.x, wv.x, bv.x);
        ov.y = fmaf(xv.y, wv.y, bv.y);
        ov.z = fmaf(xv.z, wv.z, bv.z);
        ov.w = fmaf(xv.w, wv.w, bv.w);
        o4[i] = ov;
    }
}

extern "C" void kernel_launch(void* const* d_in, const int* in_sizes, int n_in,
                              void* d_out, int out_size, void* d_ws, size_t ws_size,
                              hipStream_t stream) {
    const float* x = (const float*)d_in[0];
    const float* w = (const float*)d_in[1];
    const float* b = (const float*)d_in[2];
    float* out = (float*)d_out;

    DiagonalLinear_kernel<<<kGrid, kBlock, 0, stream>>>(x, w, b, out);
}